// Round 7
// baseline (392.206 us; speedup 1.0000x reference)
//
#include <hip/hip_runtime.h>
#include <hip/hip_bf16.h>
#include <math.h>

typedef __attribute__((ext_vector_type(8))) short bf16x8;
typedef __attribute__((ext_vector_type(4))) short bf16x4;
typedef __attribute__((ext_vector_type(4))) float f32x4;

#define NB 4096
#define ND 1024
#define INV_T 14.2857142857142857f   // 1/0.07

__device__ inline unsigned short f2bf(float x) {
    __hip_bfloat16 h = __float2bfloat16(x);
    return *reinterpret_cast<unsigned short*>(&h);
}
__device__ inline float bf2f(unsigned short u) {
    unsigned v = ((unsigned)u) << 16;
    return __uint_as_float(v);
}
__device__ inline void gload16(const void* g, void* l) {
    __builtin_amdgcn_global_load_lds(
        (const __attribute__((address_space(1))) void*)g,
        (__attribute__((address_space(3))) void*)l, 16, 0, 0);
}

// ---------------- kernel 0: L2-normalize rows, cast to bf16 -----------------
__global__ __launch_bounds__(256) void norm_kernel(
        const float* __restrict__ M, const float* __restrict__ P,
        __hip_bfloat16* __restrict__ Mn, __hip_bfloat16* __restrict__ Pn) {
    int row = blockIdx.x & (NB - 1);
    const float* src = (blockIdx.x < NB) ? M : P;
    __hip_bfloat16* dst = (blockIdx.x < NB) ? Mn : Pn;
    int tid = threadIdx.x;
    float4 v = ((const float4*)(src + (size_t)row * ND))[tid];
    float ss = v.x * v.x + v.y * v.y + v.z * v.z + v.w * v.w;
    for (int off = 32; off; off >>= 1) ss += __shfl_down(ss, off);
    __shared__ float red[4];
    int lane = tid & 63, w = tid >> 6;
    if (lane == 0) red[w] = ss;
    __syncthreads();
    float rn = rsqrtf(red[0] + red[1] + red[2] + red[3]);
    ushort4 o;
    o.x = f2bf(v.x * rn); o.y = f2bf(v.y * rn);
    o.z = f2bf(v.z * rn); o.w = f2bf(v.w * rn);
    *(ushort4*)((unsigned short*)dst + (size_t)row * ND + tid * 4) = o;
}

// ---------------- kernel 1: per-row mask codes ------------------------------
__global__ __launch_bounds__(256) void key_kernel(
        const int* __restrict__ labels, const int* __restrict__ sm,
        const int* __restrict__ sp, int* __restrict__ code) {
    int i = blockIdx.x * 256 + threadIdx.x;
    if (i < NB) {
        int l = labels[i];
        code[i] = (l == 0) ? 0x40000000 : (1 + l + (sm[i] << 8) + (sp[i] << 16));
    }
}

// ------- kernel 2: fused row-sum + normalized masked weight matrix (bf16) ---
__global__ __launch_bounds__(256) void rowsumw_kernel(
        const float* __restrict__ cs, const int* __restrict__ code,
        unsigned short* __restrict__ W, float* __restrict__ flag) {
    int i = blockIdx.x;
    int ci = code[i];
    int tid = threadIdx.x;
    const float4* row = (const float4*)(cs + (size_t)i * NB);
    const int4* c4 = (const int4*)code;
    float4 v[4];
    int4 cj[4];
    float s = 0.f;
#pragma unroll
    for (int k = 0; k < 4; ++k) {
        int t = tid + k * 256;
        v[k] = row[t];
        cj[k] = c4[t];
        int j = t * 4;
        if (cj[k].x == ci && j + 0 != i) s += v[k].x;
        if (cj[k].y == ci && j + 1 != i) s += v[k].y;
        if (cj[k].z == ci && j + 2 != i) s += v[k].z;
        if (cj[k].w == ci && j + 3 != i) s += v[k].w;
    }
    for (int off = 1; off < 64; off <<= 1) s += __shfl_xor(s, off);
    __shared__ float red[4];
    int lane = tid & 63, w = tid >> 6;
    if (lane == 0) red[w] = s;
    __syncthreads();
    float tot = red[0] + red[1] + red[2] + red[3];
    float inv = (tot > 0.f) ? 1.f / tot : 0.f;
#pragma unroll
    for (int k = 0; k < 4; ++k) {
        int t = tid + k * 256;
        int j = t * 4;
        ushort4 o;
        o.x = (cj[k].x == ci && j + 0 != i) ? f2bf(v[k].x * inv) : (unsigned short)0;
        o.y = (cj[k].y == ci && j + 1 != i) ? f2bf(v[k].y * inv) : (unsigned short)0;
        o.z = (cj[k].z == ci && j + 2 != i) ? f2bf(v[k].z * inv) : (unsigned short)0;
        o.w = (cj[k].w == ci && j + 3 != i) ? f2bf(v[k].w * inv) : (unsigned short)0;
        *(ushort4*)&W[(size_t)i * NB + j] = o;
    }
    if (tid == 0) flag[i] = (tot > 0.f) ? 1.f : 0.f;
}

// ---------------- kernel 3: fused 256x256-tile GEMM + loss epilogue ---------
// 528 logical blocks (XCD-chunk swizzled): b<256 cross (S1=Mn Pn^T, 16x16);
// b>=256 symmetric upper-tri (Mn then Pn, 136 each).
// 1024 threads = 16 waves (4x4), wave tile 64x64, acc[4][4] = 64 VGPR/lane
// (fits the 128-reg hard cap of 1024-thread blocks -> no scratch spill).
// K loop: BK=64 (128B rows, XOR-swizzled), 2 x 64KB LDS dbuf, counted vmcnt.
// Epilogue: full 256x256 W tile staged in 128KB LDS (d1), then W^T (d2).
__global__ __launch_bounds__(1024) void mega_gemm(
        const __hip_bfloat16* __restrict__ Mn, const __hip_bfloat16* __restrict__ Pn,
        const unsigned short* __restrict__ Wg,
        float* __restrict__ rowsum1, float* __restrict__ colsum1,
        float* __restrict__ rowsum3, float* __restrict__ rowsum4,
        float* __restrict__ dots) {
    __shared__ char smem[131072] __attribute__((aligned(16)));

    int tid = threadIdx.x;
    int lane = tid & 63, w = tid >> 6;       // w: 0..15
    int wm = w >> 2, wn = w & 3;             // 4x4 wave grid, tile 64x64
    int lr = lane & 15, lg = lane >> 4;

    // ---- block decode (XCD-chunked swizzle: 528 = 8 * 66, bijective) ----
    int b = (blockIdx.x & 7) * 66 + (blockIdx.x >> 3);
    int bi, bj, mode;
    const __hip_bfloat16 *A, *Bm;
    if (b < 256) {
        bi = b >> 4; bj = b & 15; A = Mn; Bm = Pn; mode = 0;
    } else {
        int t = b - 256;
        int md = (t >= 136) ? 1 : 0;
        t -= md * 136;
        bi = 0;
        while (t >= 16 - bi) { t -= 16 - bi; ++bi; }
        bj = bi + t;
        A = md ? Pn : Mn; Bm = A;
        mode = 1 + md;
    }
    bool offdiag = (mode == 0) || (bi != bj);
    size_t rowBase = (size_t)bi * 256;
    size_t colBase = (size_t)bj * 256;
    float* rowTgt = (mode == 0) ? rowsum1 : ((mode == 1) ? rowsum3 : rowsum4);
    float* colTgt = (mode == 0) ? colsum1 : rowTgt;

    // ---- staging addresses: pre-swizzled source (chunk ^= row&7) ----
    int sr8 = lane >> 3;                       // row within 8-row issue
    int sch = ((lane & 7) ^ sr8) * 8;          // bf16 elems (16B chunks)
    const __hip_bfloat16* gA = A + (rowBase + w * 16 + sr8) * ND + sch;
    const __hip_bfloat16* gB = Bm + (colBase + w * 16 + sr8) * ND + sch;

    f32x4 acc[4][4] = {};

    // per STAGE each thread issues 4 gload16 (2 A-rows-of-8 + 2 B)
#define STAGE(bufi, t) {                                                   \
        int k0 = (t) * 64;                                                 \
        char* base = smem + (bufi) * 65536;                                \
        _Pragma("unroll")                                                  \
        for (int c = 0; c < 2; ++c) {                                      \
            gload16(gA + (size_t)c * 8 * ND + k0, base + (w * 2 + c) * 1024);          \
            gload16(gB + (size_t)c * 8 * ND + k0, base + 32768 + (w * 2 + c) * 1024);  \
        }                                                                  \
    }
#define COMPUTE(bufi) {                                                    \
        const __hip_bfloat16* sA = (const __hip_bfloat16*)(smem + (bufi) * 65536); \
        const __hip_bfloat16* sB = sA + 16384;                             \
        _Pragma("unroll")                                                  \
        for (int ks = 0; ks < 2; ++ks) {                                   \
            int cp = ((ks * 4 + lg) ^ (lr & 7)) * 8;                       \
            bf16x8 av[4], bv[4];                                           \
            _Pragma("unroll")                                              \
            for (int n = 0; n < 4; ++n)                                    \
                bv[n] = *(const bf16x8*)&sB[(wn * 64 + n * 16 + lr) * 64 + cp]; \
            _Pragma("unroll")                                              \
            for (int i = 0; i < 4; ++i)                                    \
                av[i] = *(const bf16x8*)&sA[(wm * 64 + i * 16 + lr) * 64 + cp]; \
            _Pragma("unroll")                                              \
            for (int i = 0; i < 4; ++i)                                    \
                _Pragma("unroll")                                          \
                for (int n = 0; n < 4; ++n)                                \
                    acc[i][n] = __builtin_amdgcn_mfma_f32_16x16x32_bf16(   \
                        av[i], bv[n], acc[i][n], 0, 0, 0);                 \
        }                                                                  \
    }
#define BAR __builtin_amdgcn_s_barrier()

    STAGE(0, 0); STAGE(1, 1);
    asm volatile("s_waitcnt vmcnt(4)" ::: "memory"); BAR;
    int cur = 0;
    for (int t = 0; t < 14; ++t) {
        COMPUTE(cur); BAR;
        STAGE(cur, t + 2);
        asm volatile("s_waitcnt vmcnt(4)" ::: "memory"); BAR;
        cur ^= 1;
    }
    COMPUTE(cur);
    asm volatile("s_waitcnt vmcnt(0)" ::: "memory"); BAR;
    COMPUTE(cur ^ 1);
    __syncthreads();
#undef STAGE
#undef COMPUTE

    // ---- epilogue ----
    unsigned short* wl = (unsigned short*)smem;
    float d1 = 0.f, d2 = 0.f;
    float cexp[4] = {0.f, 0.f, 0.f, 0.f};

    // stage FULL W[i][j] tile: 256 rows x 256 cols bf16 = 128KB, swizzled
#pragma unroll
    for (int c = 0; c < 8; ++c) {
        int q = w * 8 + c;                             // 0..127 (1KB issues)
        int sr = 2 * q + (lane >> 5);                  // W row 0..255
        int gchunk = (lane & 31) ^ (sr & 7);           // source pre-swizzle
        gload16(Wg + (rowBase + sr) * (size_t)NB + colBase + gchunk * 8,
                smem + q * 1024);
    }
    __syncthreads();
#pragma unroll
    for (int m = 0; m < 4; ++m) {
        float rexp[4] = {0.f, 0.f, 0.f, 0.f};
#pragma unroll
        for (int n = 0; n < 4; ++n) {
            int jl = wn * 64 + n * 16 + lr;
#pragma unroll
            for (int r = 0; r < 4; ++r) {
                int rl = wm * 64 + m * 16 + lg * 4 + r;
                float sim = acc[m][n][r] * INV_T;
                float e = __expf(sim - INV_T);
                rexp[r] += e;
                cexp[n] += e;
                int ck = (jl >> 3) ^ (rl & 7);
                d1 += bf2f(wl[rl * 256 + ck * 8 + (jl & 7)]) * sim;
            }
        }
#pragma unroll
        for (int r = 0; r < 4; ++r) {
            float v = rexp[r];
            v += __shfl_xor(v, 1); v += __shfl_xor(v, 2);
            v += __shfl_xor(v, 4); v += __shfl_xor(v, 8);
            if (lr == 0)
                atomicAdd(&rowTgt[rowBase + wm * 64 + m * 16 + lg * 4 + r], v);
        }
    }
    __syncthreads();

    if (offdiag) {
#pragma unroll
        for (int n = 0; n < 4; ++n) {
            float v = cexp[n];
            v += __shfl_xor(v, 16); v += __shfl_xor(v, 32);
            if (lg == 0)
                atomicAdd(&colTgt[colBase + wn * 64 + n * 16 + lr], v);
        }
        // stage FULL W[j][i] tile: rows jl 0..255, cols il 0..255
#pragma unroll
        for (int c = 0; c < 8; ++c) {
            int q = w * 8 + c;
            int sr = 2 * q + (lane >> 5);              // jl row 0..255
            int gchunk = (lane & 31) ^ (sr & 7);
            gload16(Wg + (colBase + sr) * (size_t)NB + rowBase + gchunk * 8,
                    smem + q * 1024);
        }
        __syncthreads();
#pragma unroll
        for (int m = 0; m < 4; ++m) {
            int il0 = wm * 64 + m * 16 + lg * 4;
#pragma unroll
            for (int n = 0; n < 4; ++n) {
                int jl = wn * 64 + n * 16 + lr;
                int ck = (il0 >> 3) ^ (jl & 7);
                bf16x4 wv = *(const bf16x4*)&wl[jl * 256 + ck * 8 + (il0 & 7)];
#pragma unroll
                for (int r = 0; r < 4; ++r)
                    d2 += bf2f((unsigned short)wv[r]) * (acc[m][n][r] * INV_T);
            }
        }
    }

    if (mode == 0) {
        for (int off = 32; off; off >>= 1) {
            d1 += __shfl_xor(d1, off);
            d2 += __shfl_xor(d2, off);
        }
        if (lane == 0) {
            atomicAdd(&dots[0], d1);
            atomicAdd(&dots[1], d2);
        }
    } else {
        float dtot = d1 + (offdiag ? d2 : 0.f);
        for (int off = 32; off; off >>= 1) dtot += __shfl_xor(dtot, off);
        if (lane == 0) atomicAdd(&dots[1 + mode], dtot);
    }
}

// ---------------- kernel 4: finalize --------------------------------------
__global__ __launch_bounds__(256) void finalize_kernel(
        const float* __restrict__ rowsum1, const float* __restrict__ colsum1,
        const float* __restrict__ rowsum3, const float* __restrict__ rowsum4,
        const float* __restrict__ flag, const float* __restrict__ dots,
        float* __restrict__ out) {
    int tid = threadIdx.x;
    float l = 0.f;
    for (int i = tid; i < NB; i += 256) {
        if (flag[i] != 0.f) {
            l += 4.f * INV_T + logf(rowsum1[i]) + logf(colsum1[i]) +
                 logf(rowsum3[i]) + logf(rowsum4[i]);
        }
    }
    for (int off = 32; off; off >>= 1) l += __shfl_down(l, off);
    __shared__ float red[4];
    int lane = tid & 63, w = tid >> 6;
    if (lane == 0) red[w] = l;
    __syncthreads();
    if (tid == 0) {
        float L = red[0] + red[1] + red[2] + red[3];
        float dt = dots[0] + dots[1] + dots[2] + dots[3];
        out[0] = (L - dt) / (4.0f * (float)NB);
    }
}

extern "C" void kernel_launch(void* const* d_in, const int* in_sizes, int n_in,
                              void* d_out, int out_size, void* d_ws, size_t ws_size,
                              hipStream_t stream) {
    const float* M = (const float*)d_in[0];
    const float* P = (const float*)d_in[1];
    const int* labels = (const int*)d_in[2];
    const int* sm = (const int*)d_in[3];
    const int* sp = (const int*)d_in[4];
    const float* cs = (const float*)d_in[5];
    float* out = (float*)d_out;

    char* ws = (char*)d_ws;
    __hip_bfloat16* Mn = (__hip_bfloat16*)ws;                              // 8 MB
    __hip_bfloat16* Pn = (__hip_bfloat16*)(ws + (size_t)8 * 1024 * 1024);  // 8 MB
    unsigned short* W = (unsigned short*)(ws + (size_t)16 * 1024 * 1024);  // 32 MB
    char* p = ws + (size_t)48 * 1024 * 1024;
    int* code = (int*)p;        p += 16384;
    float* flag = (float*)p;    p += 16384;
    float* rowsum1 = (float*)p; p += 16384;
    float* colsum1 = (float*)p; p += 16384;
    float* rowsum3 = (float*)p; p += 16384;
    float* rowsum4 = (float*)p; p += 16384;
    float* dots = (float*)p;

    hipMemsetAsync(rowsum1, 0, 4 * 16384 + 256, stream);

    norm_kernel<<<2 * NB, 256, 0, stream>>>(M, P, Mn, Pn);
    key_kernel<<<NB / 256, 256, 0, stream>>>(labels, sm, sp, code);
    rowsumw_kernel<<<NB, 256, 0, stream>>>(cs, code, W, flag);

    mega_gemm<<<528, 1024, 0, stream>>>(Mn, Pn, W, rowsum1, colsum1,
                                        rowsum3, rowsum4, dots);

    finalize_kernel<<<1, 256, 0, stream>>>(rowsum1, colsum1, rowsum3, rowsum4,
                                           flag, dots, out);
}

// Round 8
// 287.459 us; speedup vs baseline: 1.3644x; 1.3644x over previous
//
#include <hip/hip_runtime.h>
#include <hip/hip_bf16.h>
#include <math.h>

typedef __attribute__((ext_vector_type(8))) short bf16x8;
typedef __attribute__((ext_vector_type(4))) short bf16x4;
typedef __attribute__((ext_vector_type(4))) float f32x4;

#define NB 4096
#define ND 1024
#define INV_T 14.2857142857142857f   // 1/0.07
#define WPITCH 136                   // bf16 elems: 272B rows, 16B aligned

__device__ inline unsigned short f2bf(float x) {
    __hip_bfloat16 h = __float2bfloat16(x);
    return *reinterpret_cast<unsigned short*>(&h);
}
__device__ inline float bf2f(unsigned short u) {
    unsigned v = ((unsigned)u) << 16;
    return __uint_as_float(v);
}
__device__ inline void gload16(const void* g, void* l) {
    __builtin_amdgcn_global_load_lds(
        (const __attribute__((address_space(1))) void*)g,
        (__attribute__((address_space(3))) void*)l, 16, 0, 0);
}

// ---------------- kernel 0: L2-normalize rows, cast to bf16 -----------------
__global__ __launch_bounds__(256) void norm_kernel(
        const float* __restrict__ M, const float* __restrict__ P,
        __hip_bfloat16* __restrict__ Mn, __hip_bfloat16* __restrict__ Pn) {
    int row = blockIdx.x & (NB - 1);
    const float* src = (blockIdx.x < NB) ? M : P;
    __hip_bfloat16* dst = (blockIdx.x < NB) ? Mn : Pn;
    int tid = threadIdx.x;
    float4 v = ((const float4*)(src + (size_t)row * ND))[tid];
    float ss = v.x * v.x + v.y * v.y + v.z * v.z + v.w * v.w;
    for (int off = 32; off; off >>= 1) ss += __shfl_down(ss, off);
    __shared__ float red[4];
    int lane = tid & 63, w = tid >> 6;
    if (lane == 0) red[w] = ss;
    __syncthreads();
    float rn = rsqrtf(red[0] + red[1] + red[2] + red[3]);
    ushort4 o;
    o.x = f2bf(v.x * rn); o.y = f2bf(v.y * rn);
    o.z = f2bf(v.z * rn); o.w = f2bf(v.w * rn);
    *(ushort4*)((unsigned short*)dst + (size_t)row * ND + tid * 4) = o;
}

// ---------------- kernel 1: per-row mask codes ------------------------------
__global__ __launch_bounds__(256) void key_kernel(
        const int* __restrict__ labels, const int* __restrict__ sm,
        const int* __restrict__ sp, int* __restrict__ code) {
    int i = blockIdx.x * 256 + threadIdx.x;
    if (i < NB) {
        int l = labels[i];
        code[i] = (l == 0) ? 0x40000000 : (1 + l + (sm[i] << 8) + (sp[i] << 16));
    }
}

// ------- kernel 2: fused row-sum + normalized masked weight matrix (bf16) ---
__global__ __launch_bounds__(256) void rowsumw_kernel(
        const float* __restrict__ cs, const int* __restrict__ code,
        unsigned short* __restrict__ W, float* __restrict__ flag) {
    int i = blockIdx.x;
    int ci = code[i];
    int tid = threadIdx.x;
    const float4* row = (const float4*)(cs + (size_t)i * NB);
    const int4* c4 = (const int4*)code;
    float4 v[4];
    int4 cj[4];
    float s = 0.f;
#pragma unroll
    for (int k = 0; k < 4; ++k) {
        int t = tid + k * 256;
        v[k] = row[t];
        cj[k] = c4[t];
        int j = t * 4;
        if (cj[k].x == ci && j + 0 != i) s += v[k].x;
        if (cj[k].y == ci && j + 1 != i) s += v[k].y;
        if (cj[k].z == ci && j + 2 != i) s += v[k].z;
        if (cj[k].w == ci && j + 3 != i) s += v[k].w;
    }
    for (int off = 1; off < 64; off <<= 1) s += __shfl_xor(s, off);
    __shared__ float red[4];
    int lane = tid & 63, w = tid >> 6;
    if (lane == 0) red[w] = s;
    __syncthreads();
    float tot = red[0] + red[1] + red[2] + red[3];
    float inv = (tot > 0.f) ? 1.f / tot : 0.f;
#pragma unroll
    for (int k = 0; k < 4; ++k) {
        int t = tid + k * 256;
        int j = t * 4;
        ushort4 o;
        o.x = (cj[k].x == ci && j + 0 != i) ? f2bf(v[k].x * inv) : (unsigned short)0;
        o.y = (cj[k].y == ci && j + 1 != i) ? f2bf(v[k].y * inv) : (unsigned short)0;
        o.z = (cj[k].z == ci && j + 2 != i) ? f2bf(v[k].z * inv) : (unsigned short)0;
        o.w = (cj[k].w == ci && j + 3 != i) ? f2bf(v[k].w * inv) : (unsigned short)0;
        *(ushort4*)&W[(size_t)i * NB + j] = o;
    }
    if (tid == 0) flag[i] = (tot > 0.f) ? 1.f : 0.f;
}

// ---------------- kernel 3: GEMM + fused softmax/loss epilogue --------------
// 128x128 tile, 256 threads (4 waves 2x2, wave tile 64x64, acc[4][4]=64 AGPR,
// arch VGPR ~115 -> no spill regime, proven R1-R3).
// K loop: BK=64, 2x32KB LDS double-buffer, counted vmcnt(8) prefetch (T3/T4).
// SYM=0: S1 = Mn Pn^T, grid (32,32).  d1->dots[0], d2->dots[1],
//        rexp->rs0(rowsum1), cexp->colsum1.
// SYM=1: S = F F^T (F = Mn or Pn by blockIdx.y), upper-tri grid (528,2).
//        rexp->rowsum[row]; offdiag adds cexp->rowsum[col], d1+d2->dots[2+y].
template <int SYM>
__global__ __launch_bounds__(256) void gemm_fused(
        const __hip_bfloat16* __restrict__ F0, const __hip_bfloat16* __restrict__ F1,
        const unsigned short* __restrict__ Wg,
        float* __restrict__ rs0, float* __restrict__ rs1,
        float* __restrict__ colsum, float* __restrict__ dots) {
    __shared__ char smem[65536] __attribute__((aligned(16)));
    unsigned short* wl = (unsigned short*)smem;

    int tid = threadIdx.x;
    int lane = tid & 63;
    int wid = tid >> 6;
    int wm = wid >> 1, wn = wid & 1;
    int lr = lane & 15, lg = lane >> 4;

    int bi, bj;
    const __hip_bfloat16 *A, *Bm;
    float* rowTgt;
    if (SYM == 0) {
        bi = blockIdx.y; bj = blockIdx.x;
        A = F0; Bm = F1; rowTgt = rs0;
    } else {
        int t = blockIdx.x;
        bi = 0;
        while (t >= 32 - bi) { t -= 32 - bi; ++bi; }
        bj = bi + t;
        A = blockIdx.y ? F1 : F0; Bm = A;
        rowTgt = blockIdx.y ? rs1 : rs0;
    }
    bool offdiag = (SYM != 0) && (bi != bj);
    bool doCol = (SYM == 0) || offdiag;
    size_t rowBase = (size_t)bi * 128;
    size_t colBase = (size_t)bj * 128;

    // ---- staging addrs: pre-swizzled global chunk (lane&7)^(row&7) ----
    int lrow = lane >> 3;                 // 0..7
    int lchunk = (lane & 7) ^ lrow;       // pre-swizzled 16B chunk
    const __hip_bfloat16* gA = A + (rowBase + wid * 32 + lrow) * ND + lchunk * 8;
    const __hip_bfloat16* gB = Bm + (colBase + wid * 32 + lrow) * ND + lchunk * 8;
    int rxor = lr & 7;                    // read-side chunk xor (row&7)

    f32x4 acc[4][4] = {};

#define STAGE(bufi, t) {                                                    \
        int k0 = (t) * 64;                                                  \
        char* base = smem + (bufi) * 32768;                                 \
        _Pragma("unroll")                                                   \
        for (int c = 0; c < 4; ++c) {                                       \
            gload16(gA + (size_t)c * 8 * ND + k0, base + (wid * 4 + c) * 1024);          \
            gload16(gB + (size_t)c * 8 * ND + k0, base + 16384 + (wid * 4 + c) * 1024);  \
        }                                                                   \
    }
#define COMPUTE(bufi) {                                                     \
        const __hip_bfloat16* sA = (const __hip_bfloat16*)(smem + (bufi) * 32768); \
        const __hip_bfloat16* sB = sA + 8192;                               \
        _Pragma("unroll")                                                   \
        for (int ks = 0; ks < 2; ++ks) {                                    \
            bf16x8 av[4], bv[4];                                            \
            int coff = ((ks * 4 + lg) ^ rxor) * 8;                          \
            _Pragma("unroll")                                               \
            for (int m = 0; m < 4; ++m)                                     \
                av[m] = *(const bf16x8*)&sA[(wm * 64 + m * 16 + lr) * 64 + coff]; \
            _Pragma("unroll")                                               \
            for (int n = 0; n < 4; ++n)                                     \
                bv[n] = *(const bf16x8*)&sB[(wn * 64 + n * 16 + lr) * 64 + coff]; \
            _Pragma("unroll")                                               \
            for (int m = 0; m < 4; ++m)                                     \
                _Pragma("unroll")                                           \
                for (int n = 0; n < 4; ++n)                                 \
                    acc[m][n] = __builtin_amdgcn_mfma_f32_16x16x32_bf16(    \
                        av[m], bv[n], acc[m][n], 0, 0, 0);                  \
        }                                                                   \
    }
#define BAR __builtin_amdgcn_s_barrier()

    // prologue: 2 tiles in flight
    STAGE(0, 0); STAGE(1, 1);
    asm volatile("s_waitcnt vmcnt(8)" ::: "memory"); BAR;   // buf0 ready
    // steady state: compute t, refill its buffer with t+2, wait for t+1
#pragma unroll 2
    for (int t = 0; t < 14; ++t) {
        COMPUTE(t & 1);
        BAR;                               // all waves done reading buf
        STAGE(t & 1, t + 2);
        asm volatile("s_waitcnt vmcnt(8)" ::: "memory"); BAR;  // next buf ready
    }
    COMPUTE(0);                            // step 14
    asm volatile("s_waitcnt vmcnt(0)" ::: "memory"); BAR;
    COMPUTE(1);                            // step 15
    __syncthreads();
#undef STAGE
#undef COMPUTE
#undef BAR

    // ---- epilogue (validated R3): stage W[i][j] tile ([il][jl], WPITCH) ----
#pragma unroll
    for (int r8 = 0; r8 < 8; ++r8) {
        int il = r8 * 16 + (tid >> 4);
        int jl = (tid & 15) * 8;
        *(int4*)&wl[il * WPITCH + jl] =
            *(const int4*)&Wg[(rowBase + il) * (size_t)NB + colBase + jl];
    }
    __syncthreads();

    float d1 = 0.f, d2 = 0.f;
    float cexp[4] = {0.f, 0.f, 0.f, 0.f};
#pragma unroll
    for (int m = 0; m < 4; ++m) {
        float rexp[4] = {0.f, 0.f, 0.f, 0.f};
#pragma unroll
        for (int n = 0; n < 4; ++n) {
            int jl = wn * 64 + n * 16 + lr;
#pragma unroll
            for (int r = 0; r < 4; ++r) {
                int il = wm * 64 + m * 16 + lg * 4 + r;
                float sim = acc[m][n][r] * INV_T;
                float e = __expf(sim - INV_T);
                rexp[r] += e;
                cexp[n] += e;
                d1 += bf2f(wl[il * WPITCH + jl]) * sim;
            }
        }
#pragma unroll
        for (int r = 0; r < 4; ++r) {
            float v = rexp[r];
            v += __shfl_xor(v, 1); v += __shfl_xor(v, 2);
            v += __shfl_xor(v, 4); v += __shfl_xor(v, 8);
            if (lr == 0)
                atomicAdd(&rowTgt[rowBase + wm * 64 + m * 16 + lg * 4 + r], v);
        }
    }
    if (doCol) {
        float* ctgt = (SYM == 0) ? colsum : rowTgt;
#pragma unroll
        for (int n = 0; n < 4; ++n) {
            float v = cexp[n];
            v += __shfl_xor(v, 16); v += __shfl_xor(v, 32);
            if (lg == 0)
                atomicAdd(&ctgt[colBase + wn * 64 + n * 16 + lr], v);
        }
    }

    // ---- d2: stage W[j][i] tile ([jl][il], WPITCH) ----
    if ((SYM == 0) || offdiag) {
        __syncthreads();
#pragma unroll
        for (int r8 = 0; r8 < 8; ++r8) {
            int jl = r8 * 16 + (tid >> 4);
            int il = (tid & 15) * 8;
            *(int4*)&wl[jl * WPITCH + il] =
                *(const int4*)&Wg[(colBase + jl) * (size_t)NB + rowBase + il];
        }
        __syncthreads();
#pragma unroll
        for (int m = 0; m < 4; ++m) {
            int il0 = wm * 64 + m * 16 + lg * 4;
#pragma unroll
            for (int n = 0; n < 4; ++n) {
                int jl = wn * 64 + n * 16 + lr;
                bf16x4 wv = *(const bf16x4*)&wl[jl * WPITCH + il0];
#pragma unroll
                for (int r = 0; r < 4; ++r)
                    d2 += bf2f((unsigned short)wv[r]) * (acc[m][n][r] * INV_T);
            }
        }
    }

    if (SYM == 0) {
        for (int off = 32; off; off >>= 1) {
            d1 += __shfl_xor(d1, off);
            d2 += __shfl_xor(d2, off);
        }
        if (lane == 0) {
            atomicAdd(&dots[0], d1);
            atomicAdd(&dots[1], d2);
        }
    } else {
        float dtot = d1 + (offdiag ? d2 : 0.f);
        for (int off = 32; off; off >>= 1) dtot += __shfl_xor(dtot, off);
        if (lane == 0) atomicAdd(&dots[2 + blockIdx.y], dtot);
    }
}

// ---------------- kernel 4: finalize --------------------------------------
__global__ __launch_bounds__(256) void finalize_kernel(
        const float* __restrict__ rowsum1, const float* __restrict__ colsum1,
        const float* __restrict__ rowsum3, const float* __restrict__ rowsum4,
        const float* __restrict__ flag, const float* __restrict__ dots,
        float* __restrict__ out) {
    int tid = threadIdx.x;
    float l = 0.f;
    for (int i = tid; i < NB; i += 256) {
        if (flag[i] != 0.f) {
            l += 4.f * INV_T + logf(rowsum1[i]) + logf(colsum1[i]) +
                 logf(rowsum3[i]) + logf(rowsum4[i]);
        }
    }
    for (int off = 32; off; off >>= 1) l += __shfl_down(l, off);
    __shared__ float red[4];
    int lane = tid & 63, w = tid >> 6;
    if (lane == 0) red[w] = l;
    __syncthreads();
    if (tid == 0) {
        float L = red[0] + red[1] + red[2] + red[3];
        float dt = dots[0] + dots[1] + dots[2] + dots[3];
        out[0] = (L - dt) / (4.0f * (float)NB);
    }
}

extern "C" void kernel_launch(void* const* d_in, const int* in_sizes, int n_in,
                              void* d_out, int out_size, void* d_ws, size_t ws_size,
                              hipStream_t stream) {
    const float* M = (const float*)d_in[0];
    const float* P = (const float*)d_in[1];
    const int* labels = (const int*)d_in[2];
    const int* sm = (const int*)d_in[3];
    const int* sp = (const int*)d_in[4];
    const float* cs = (const float*)d_in[5];
    float* out = (float*)d_out;

    char* ws = (char*)d_ws;
    __hip_bfloat16* Mn = (__hip_bfloat16*)ws;                              // 8 MB
    __hip_bfloat16* Pn = (__hip_bfloat16*)(ws + (size_t)8 * 1024 * 1024);  // 8 MB
    unsigned short* W = (unsigned short*)(ws + (size_t)16 * 1024 * 1024);  // 32 MB
    char* p = ws + (size_t)48 * 1024 * 1024;
    int* code = (int*)p;        p += 16384;
    float* flag = (float*)p;    p += 16384;
    float* rowsum1 = (float*)p; p += 16384;
    float* colsum1 = (float*)p; p += 16384;
    float* rowsum3 = (float*)p; p += 16384;
    float* rowsum4 = (float*)p; p += 16384;
    float* dots = (float*)p;

    // zero accumulators (rowsum1..colsum1..rowsum3..rowsum4..dots contiguous)
    hipMemsetAsync(rowsum1, 0, 4 * 16384 + 256, stream);

    norm_kernel<<<2 * NB, 256, 0, stream>>>(M, P, Mn, Pn);
    key_kernel<<<NB / 256, 256, 0, stream>>>(labels, sm, sp, code);
    rowsumw_kernel<<<NB, 256, 0, stream>>>(cs, code, W, flag);

    dim3 g0(32, 32);
    gemm_fused<0><<<g0, 256, 0, stream>>>(Mn, Pn, W, rowsum1, nullptr,
                                          colsum1, dots);
    dim3 g1(528, 2);
    gemm_fused<1><<<g1, 256, 0, stream>>>(Mn, Pn, W, rowsum3, rowsum4,
                                          nullptr, dots);

    finalize_kernel<<<1, 256, 0, stream>>>(rowsum1, colsum1, rowsum3, rowsum4,
                                           flag, dots, out);
}